// Round 3
// baseline (395.287 us; speedup 1.0000x reference)
//
#include <hip/hip_runtime.h>
#include <hip/hip_bf16.h>
#include <cstdint>

// Problem constants: B=8, L=4096, D=768, Y=2048
#define BB 8
#define LL 4096
#define DD 768
#define YY 2048

typedef unsigned short u16;
typedef __bf16 bf16x8 __attribute__((ext_vector_type(8)));
typedef __bf16 bf16x2 __attribute__((ext_vector_type(2)));
typedef float f32x4 __attribute__((ext_vector_type(4)));

__device__ __forceinline__ u16 f2bf(float f) {
    uint32_t u = __float_as_uint(f);
    u += 0x7fffu + ((u >> 16) & 1u);   // RNE
    return (u16)(u >> 16);
}

__device__ __forceinline__ uint32_t pkbf(float a, float b) {
#if __has_builtin(__builtin_amdgcn_cvt_pk_bf16_f32)
    bf16x2 p = __builtin_amdgcn_cvt_pk_bf16_f32(a, b);
    return __builtin_bit_cast(uint32_t, p);
#else
    return (uint32_t)f2bf(a) | ((uint32_t)f2bf(b) << 16);
#endif
}

#define GLL(src, dst) \
    __builtin_amdgcn_global_load_lds((const __attribute__((address_space(1))) unsigned int*)(src), \
                                     (__attribute__((address_space(3))) unsigned int*)(dst), 16, 0, 0)

// ---------------- cast Y*D weight matrix (U or fw) to bf16 ----------------
__global__ __launch_bounds__(256) void cast_w_k(const float* __restrict__ W, u16* __restrict__ W16) {
    int i = blockIdx.x * 256 + threadIdx.x;          // one float4 per thread
    float4 v = ((const float4*)W)[i];
    uint2 h;
    h.x = pkbf(v.x, v.y); h.y = pkbf(v.z, v.w);
    ((uint2*)W16)[i] = h;
}

// ---------------- cast x (B*L*D) to bf16, pure elementwise ----------------
__global__ __launch_bounds__(256) void cast_x_k(const float* __restrict__ x, u16* __restrict__ x16) {
    int i = blockIdx.x * 256 + threadIdx.x;          // one float4 per thread
    float4 v = ((const float4*)x)[i];
    uint2 h;
    h.x = pkbf(v.x, v.y); h.y = pkbf(v.z, v.w);
    ((uint2*)x16)[i] = h;
}

// ---------------- FUSED kernel: S=U.x^T and G=fw.x^T, epilogue sum exp(S), exp(S)*G ------
// y[b,r] = sum_l exp(att[r,l]) * G[r,l] / rowsum[r]   (summation order swapped).
// R10: 128x64 2-phase -> 261 us (MfmaUtil 36). R11: counted-vmcnt alone -> neutral.
// R12: 128x128, 4 waves, per-wave 64x64 -> 224 us (MfmaUtil 41). Post-mortem: pipes
// near-serialized: per K-step-pair MFMA ~1240 cyc + LDS ~1400 cyc vs measured 2800 --
// coarse 2-barrier phases make all waves burst ds_reads together (matrix pipe idle),
// then MFMA together (LDS idle); co-resident blocks self-sync via LDS contention.
// R13: m201-faithful 8-wave fine-phase schedule (T3+T4+T5 regime):
//   - block 256l x 128y, 512 thr, 8 waves (4m x 2n), per-wave 64x64 unchanged.
//   - BK=32, 3-buf, 96 KB LDS -> 1 block/CU, 2 waves/SIMD.
//   - per K-tile: 2 sub-phases of 16 MFMA: {reads || 2 GLL} bar lgkm(0) prio1 MFMA
//     prio0 bar; counted vmcnt(4) once per tile (never 0 in main loop).
__global__ __launch_bounds__(512, 2) void fused_k(const u16* __restrict__ Xg, const u16* __restrict__ Ug,
                                                  const u16* __restrict__ Wg,
                                                  float* __restrict__ rowsum, float* __restrict__ ynum) {
    __shared__ u16 As[3 * 8192];      // x tile: 256 l-rows x 32 k (3-buf, 48 KB)
    __shared__ u16 Us[3 * 4096];      // U tile: 128 y-rows x 32 k (3-buf, 24 KB)
    __shared__ u16 Ws[3 * 4096];      // fw tile (24 KB)
    const int id = blockIdx.x;
    const int b = id & 7;             // batch pinned per XCD (%8 round-robin heuristic)
    const int r = id >> 3;            // 0..255
    const int yhalf = r >> 7;         // 0..1   (outer: U/fw half swapped once)
    const int q = r & 127;
    const int mblk = q >> 3;          // 0..15  (middle: x-tile advances, U/fw-half L2-hot)
    const int nblk = (yhalf << 3) + (q & 7);    // inner 8 y-blocks (3.1 MB wts) share x
    const u16* A = Xg + (size_t)b * LL * DD;
    rowsum += (size_t)b * YY;
    ynum   += (size_t)b * YY;
    const int m0 = mblk * 256;        // l
    const int n0 = nblk * 128;        // y
    const int t = threadIdx.x;
    const int lane = t & 63;
    const int wave = t >> 6;          // 0..7
    const int wm = (wave >> 1) * 64;  // l-offset of wave: 0,64,128,192
    const int wn = (wave & 1) * 64;   // y-offset of wave: 0,64
    const int ln = lane & 15;
    const int qd = lane >> 4;
    const int swz = (qd ^ ((ln >> 1) & 3)) * 8;   // conflict-free ds_read_b128 swizzle

    const int row = t >> 2;                              // 0..127
    const int kq0 = (t & 3) ^ ((t >> 3) & 3);            // pre-swizzled k-chunk
    const u16* Ab0 = A + (size_t)(m0 + row) * DD + kq0 * 8;        // l rows 0..127
    const u16* Ab1 = A + (size_t)(m0 + row + 128) * DD + kq0 * 8;  // l rows 128..255
    const u16* Ub0 = Ug + (size_t)(n0 + row) * DD + kq0 * 8;       // y rows 0..127
    const u16* Wb0 = Wg + (size_t)(n0 + row) * DD + kq0 * 8;
    const int c0 = t * 8, c1 = (t + 512) * 8;

    f32x4 aS[4][4] = {};
    f32x4 aG[4][4] = {};
    const int au = (wm + ln) * 32 + swz;
    const int bu = (wn + ln) * 32 + swz;

#define STAGEH1(bi) { GLL(Ab0, As + (bi) * 8192 + c0); GLL(Ub0, Us + (bi) * 4096 + c0); }
#define STAGEH2(bi) { GLL(Ab1, As + (bi) * 8192 + c1); GLL(Wb0, Ws + (bi) * 4096 + c0); \
                      Ab0 += 32; Ab1 += 32; Ub0 += 32; Wb0 += 32; }
#define WAITV(n) asm volatile("s_waitcnt vmcnt(" #n ")" ::: "memory")
#define WAITL    asm volatile("s_waitcnt lgkmcnt(0)" ::: "memory")
#define BAR      __builtin_amdgcn_s_barrier()
#define MFMA(a, bb, c) __builtin_amdgcn_mfma_f32_16x16x32_bf16(a, bb, c, 0, 0, 0)

// One K-tile = 2 sub-phases. Entry invariant: buf p staged (WAITV+BAR done), preceding
// tile's reads drained+barriered (buf d=(kt+2)%3=(kt-1)%3 is free to overwrite).
// Exit: trailing WAITV(VN); BAR establishes next tile's entry invariant.
#define KTILE(p, d, DOSTAGE, VN)                                               \
    {                                                                          \
        bf16x8 af[4], b0[4], b1[4];                                            \
        /* sub-phase 1: reads {af0-3, U01, W01} + half stage */                \
        _Pragma("unroll") for (int i = 0; i < 4; ++i)                          \
            af[i] = *(const bf16x8*)(As + (p) * 8192 + au + i * 512);          \
        b0[0] = *(const bf16x8*)(Us + (p) * 4096 + bu);                        \
        b0[1] = *(const bf16x8*)(Us + (p) * 4096 + bu + 512);                  \
        b0[2] = *(const bf16x8*)(Ws + (p) * 4096 + bu);                        \
        b0[3] = *(const bf16x8*)(Ws + (p) * 4096 + bu + 512);                  \
        if (DOSTAGE) STAGEH1(d)                                                \
        BAR;                                                                   \
        WAITL;                                                                 \
        __builtin_amdgcn_s_setprio(1);                                         \
        _Pragma("unroll") for (int i = 0; i < 4; ++i) {                        \
            aS[i][0] = MFMA(af[i], b0[0], aS[i][0]);                           \
            aG[i][0] = MFMA(af[i], b0[2], aG[i][0]);                           \
            aS[i][1] = MFMA(af[i], b0[1], aS[i][1]);                           \
            aG[i][1] = MFMA(af[i], b0[3], aG[i][1]);                           \
        }                                                                      \
        __builtin_amdgcn_s_setprio(0);                                         \
        BAR;                                                                   \
        /* sub-phase 2: reads {U23, W23} + half stage */                       \
        b1[0] = *(const bf16x8*)(Us + (p) * 4096 + bu + 1024);                 \
        b1[1] = *(const bf16x8*)(Us + (p) * 4096 + bu + 1536);                 \
        b1[2] = *(const bf16x8*)(Ws + (p) * 4096 + bu + 1024);                 \
        b1[3] = *(const bf16x8*)(Ws + (p) * 4096 + bu + 1536);                 \
        if (DOSTAGE) STAGEH2(d)                                                \
        BAR;                                                                   \
        WAITL;                                                                 \
        __builtin_amdgcn_s_setprio(1);                                         \
        _Pragma("unroll") for (int i = 0; i < 4; ++i) {                        \
            aS[i][2] = MFMA(af[i], b1[0], aS[i][2]);                           \
            aG[i][2] = MFMA(af[i], b1[2], aG[i][2]);                           \
            aS[i][3] = MFMA(af[i], b1[1], aS[i][3]);                           \
            aG[i][3] = MFMA(af[i], b1[3], aG[i][3]);                           \
        }                                                                      \
        __builtin_amdgcn_s_setprio(0);                                         \
        WAITV(VN);                                                             \
        BAR;                                                                   \
    }

    // prologue: stage tiles 0,1 (8 GLLs in flight), then wait tile0 (leave tile1's 4)
    STAGEH1(0) STAGEH2(0)
    STAGEH1(1) STAGEH2(1)
    WAITV(4);
    BAR;

    // 24 K-tiles. Tiles 0..21 stage tile kt+2 (buf (kt+2)%3); trailing WAITV(4) waits
    // tile kt+1 (leaves kt+2's 4 in flight). Tail: tile22 WAITV(0) waits tile23.
    for (int it = 0; it < 7; ++it) {         // tiles 0..20
        KTILE(0, 2, 1, 4)
        KTILE(1, 0, 1, 4)
        KTILE(2, 1, 1, 4)
    }
    KTILE(0, 2, 1, 4)                        // tile 21 (stages tile 23 -> buf 2)
    KTILE(1, 0, 0, 0)                        // tile 22 (no stage; wait tile 23)
    KTILE(2, 0, 0, 0)                        // tile 23
#undef KTILE
#undef STAGEH1
#undef STAGEH2

    // epilogue: acc[i][j][rr] -> (y = n0+wn+j*16+ln, l = m0+wm+i*16+qd*4+rr)
    #pragma unroll
    for (int j = 0; j < 4; ++j) {
        const int y = n0 + wn + j * 16 + ln;
        float rs = 0.f, ys = 0.f;
        #pragma unroll
        for (int i = 0; i < 4; ++i) {
            #pragma unroll
            for (int rr = 0; rr < 4; ++rr) {
                float e = __expf(aS[i][j][rr]);
                rs += e;
                ys += e * aG[i][j][rr];
            }
        }
        rs += __shfl_xor(rs, 16, 64);  ys += __shfl_xor(ys, 16, 64);
        rs += __shfl_xor(rs, 32, 64);  ys += __shfl_xor(ys, 32, 64);
        if (qd == 0) {
            atomicAdd(&rowsum[y], rs);
            atomicAdd(&ynum[y], ys);
        }
    }
}

// -------- finalize: y = ynum/rowsum + bias (writeback), CE loss over y --------
// one block per batch; partial NLLs combined via atomicAdd into out0 (zeroed in launch)
__global__ __launch_bounds__(256) void ce_loss_k(const float* __restrict__ ynum,
                                                 const float* __restrict__ rowsum,
                                                 const float* __restrict__ fb,
                                                 const int* __restrict__ tgt,
                                                 float* __restrict__ out0,
                                                 float* __restrict__ yv) {
    __shared__ float smx[4], ssum[4], stv[4];
    const int b = blockIdx.x;
    const int t = threadIdx.x;
    const int wave = t >> 6, lane = t & 63;
    const float* yn = ynum + b * YY;
    const float* rsm = rowsum + b * YY;
    float* row = yv + b * YY;
    const int tg = tgt[b];
    float v[8];
    float mx = -3.0e38f;
    float tv = 0.f;
    #pragma unroll
    for (int i = 0; i < 8; ++i) {
        const int idx = t + 256 * i;
        v[i] = yn[idx] / rsm[idx] + fb[idx];
        row[idx] = v[i];                    // write final y
        mx = fmaxf(mx, v[i]);
        if (idx == tg) tv = v[i];
    }
    // block-reduce max
    #pragma unroll
    for (int o = 32; o; o >>= 1) mx = fmaxf(mx, __shfl_xor(mx, o, 64));
    if (lane == 0) smx[wave] = mx;
    __syncthreads();
    mx = fmaxf(fmaxf(smx[0], smx[1]), fmaxf(smx[2], smx[3]));
    float s = 0.f;
    #pragma unroll
    for (int i = 0; i < 8; ++i) s += __expf(v[i] - mx);
    #pragma unroll
    for (int o = 32; o; o >>= 1) { s += __shfl_xor(s, o, 64); tv += __shfl_xor(tv, o, 64); }
    if (lane == 0) { ssum[wave] = s; stv[wave] = tv; }
    __syncthreads();
    if (t == 0) {
        float st = ssum[0] + ssum[1] + ssum[2] + ssum[3];
        float tt = stv[0] + stv[1] + stv[2] + stv[3];
        atomicAdd(out0, (mx + logf(st) - tt) * 0.125f);
    }
}

extern "C" void kernel_launch(void* const* d_in, const int* in_sizes, int n_in,
                              void* d_out, int out_size, void* d_ws, size_t ws_size,
                              hipStream_t stream) {
    const float* x   = (const float*)d_in[0];   // (B,L,D)
    const float* Uw  = (const float*)d_in[1];   // (Y,D)
    const float* fw  = (const float*)d_in[2];   // (Y,D)
    const float* fb  = (const float*)d_in[3];   // (Y,)
    const int*   tgt = (const int*)d_in[4];     // (B,)
    float* out = (float*)d_out;                 // [loss, y(B*Y)]

    char* ws = (char*)d_ws;
    u16*  x16  = (u16*)(ws);                          // B*L*D bf16 = 50,331,648 B
    u16*  U16  = (u16*)(ws + 50331648);               // Y*D bf16   =  3,145,728 B
    u16*  fw16 = (u16*)(ws + 53477376);               // Y*D bf16   =  3,145,728 B
    float* rowsum = (float*)(ws + 56623104);          // B*Y fp32   =     65,536 B
    float* ynum   = (float*)(ws + 56688640);          // B*Y fp32   =     65,536 B

    hipMemsetAsync(rowsum, 0, 2 * (size_t)BB * YY * sizeof(float), stream);  // rowsum+ynum
    hipMemsetAsync(out, 0, sizeof(float), stream);                           // loss accumulator
    cast_w_k<<<1536, 256, 0, stream>>>(Uw, U16);
    cast_w_k<<<1536, 256, 0, stream>>>(fw, fw16);
    cast_x_k<<<(BB * LL * DD) / 1024, 256, 0, stream>>>(x, x16);

    // Fused S/G GEMM + exp + reductions: 2048 blocks (256l x 128y tiles, 512 thr),
    // L2-resident-weights order
    fused_k<<<(LL / 256) * (YY / 128) * BB, 512, 0, stream>>>(x16, U16, fw16, rowsum, ynum);

    ce_loss_k<<<BB, 256, 0, stream>>>(ynum, rowsum, fb, tgt, out, out + 1);
}